// Round 7
// baseline (218.179 us; speedup 1.0000x reference)
//
#include <hip/hip_runtime.h>
#include <math.h>

#define DEV __device__ __forceinline__

constexpr int N_TRAIN = 131072;
constexpr int M_TEST  = 65536;
constexpr int T_TOT   = N_TRAIN + M_TEST;  // 196608
constexpr int TPB     = 64;                // single-wave blocks
constexpr int NBLK    = T_TOT / TPB;       // 3072 blocks -> 12 blocks/CU
constexpr int MIDT    = 512;               // mid-scan block size
constexpr int MPT     = NBLK / MIDT;       // 6 aggregates per mid thread
constexpr int FE_S    = 33;                // FE stride (floats)
constexpr int SE_S    = 19;                // SE LDS stride (18 + pad)

// ---------------- 3x3 helpers (row-major float[9]) ----------------
DEV void mm(const float* X, const float* Y, float* Z) {
#pragma unroll
  for (int i = 0; i < 3; ++i)
#pragma unroll
    for (int j = 0; j < 3; ++j)
      Z[i*3+j] = X[i*3]*Y[j] + X[i*3+1]*Y[3+j] + X[i*3+2]*Y[6+j];
}
DEV void mmnt(const float* X, const float* Y, float* Z) { // X * Y^T
#pragma unroll
  for (int i = 0; i < 3; ++i)
#pragma unroll
    for (int j = 0; j < 3; ++j)
      Z[i*3+j] = X[i*3]*Y[j*3] + X[i*3+1]*Y[j*3+1] + X[i*3+2]*Y[j*3+2];
}
DEV void mtn(const float* X, const float* Y, float* Z) { // X^T * Y
#pragma unroll
  for (int i = 0; i < 3; ++i)
#pragma unroll
    for (int j = 0; j < 3; ++j)
      Z[i*3+j] = X[i]*Y[j] + X[3+i]*Y[3+j] + X[6+i]*Y[6+j];
}
DEV void mv(const float* X, const float* v, float* w) {
#pragma unroll
  for (int i = 0; i < 3; ++i) w[i] = X[i*3]*v[0] + X[i*3+1]*v[1] + X[i*3+2]*v[2];
}
DEV void mtv(const float* X, const float* v, float* w) {
#pragma unroll
  for (int i = 0; i < 3; ++i) w[i] = X[i]*v[0] + X[3+i]*v[1] + X[6+i]*v[2];
}
// inverse with double cofactors (cancellation hedge); in/out fp32
DEV void inv3(const float* mf_, float* o) {
  double m0=mf_[0], m1=mf_[1], m2=mf_[2], m3=mf_[3], m4=mf_[4],
         m5=mf_[5], m6=mf_[6], m7=mf_[7], m8=mf_[8];
  double c00 = m4*m8 - m5*m7;
  double c10 = m5*m6 - m3*m8;
  double c20 = m3*m7 - m4*m6;
  double det = m0*c00 + m1*c10 + m2*c20;
  double id = 1.0 / det;
  o[0] = (float)(c00*id); o[1] = (float)((m2*m7-m1*m8)*id); o[2] = (float)((m1*m5-m2*m4)*id);
  o[3] = (float)(c10*id); o[4] = (float)((m0*m8-m2*m6)*id); o[5] = (float)((m2*m3-m0*m5)*id);
  o[6] = (float)(c20*id); o[7] = (float)((m1*m6-m0*m7)*id); o[8] = (float)((m0*m4-m1*m3)*id);
}
DEV void symm(float* P) {
  float a = 0.5f*(P[1]+P[3]), b = 0.5f*(P[2]+P[6]), c = 0.5f*(P[5]+P[7]);
  P[1]=P[3]=a; P[2]=P[6]=b; P[5]=P[7]=c;
}

// ---------------- model ----------------
struct Model { float lam, v, kap, l4; };
DEV Model make_model(const float* varp, const float* ellp) {
  Model M; M.v = varp[0];
  float ell = ellp[0];
  M.lam = sqrtf(5.0f) / ell;
  M.kap = M.lam * M.lam / 3.0f;
  float l2 = M.lam * M.lam;
  M.l4 = l2 * l2;
  return M;
}
DEV void pinf(const Model& M, float* P) {
  float vk = M.v * M.kap;
  P[0]=M.v; P[1]=0;  P[2]=-vk;
  P[3]=0;   P[4]=vk; P[5]=0;
  P[6]=-vk; P[7]=0;  P[8]=M.v*M.l4;
}
// A = exp(dt*F) = e^{-lam dt}(I + dt*N + dt^2/2 N^2); Q = Pinf - A Pinf A^T
DEV void make_AQ(const Model& M, float dt, float* A, float* Q) {
  float lam = M.lam, l2 = lam*lam, l3 = l2*lam, l4 = M.l4;
  float e = __expf(-lam * dt);
  float h = 0.5f * dt * dt;
  A[0] = e*(1.0f + dt*lam + h*l2);
  A[1] = e*(dt + 2.0f*h*lam);
  A[2] = e*h;
  A[3] = e*(-h*l3);
  A[4] = e*(1.0f + dt*lam - 2.0f*h*l2);
  A[5] = e*(dt - h*lam);
  A[6] = e*(-dt*l3 + h*l4);
  A[7] = e*(-3.0f*dt*l2 + 2.0f*h*l3);
  A[8] = e*(1.0f - 2.0f*dt*lam + h*l2);
  float vk = M.v * M.kap, vl4 = M.v * M.l4;
  float B[9];  // A * Pinf
#pragma unroll
  for (int i = 0; i < 3; ++i) {
    B[i*3+0] =  A[i*3+0]*M.v - A[i*3+2]*vk;
    B[i*3+1] =  A[i*3+1]*vk;
    B[i*3+2] = -A[i*3+0]*vk  + A[i*3+2]*vl4;
  }
  float Pi[9]; pinf(M, Pi);
#pragma unroll
  for (int i = 0; i < 3; ++i)
#pragma unroll
    for (int j = 0; j < 3; ++j)
      Q[i*3+j] = Pi[i*3+j] - (B[i*3]*A[j*3] + B[i*3+1]*A[j*3+1] + B[i*3+2]*A[j*3+2]);
}

// ---------------- filter scan element (Sarkka/Garcia-Fernandez) ----------------
struct FE { float A[9]; float b[3]; float C[9]; float h[3]; float J[9]; };

DEV FE fe_identity() {
  FE e;
#pragma unroll
  for (int i=0;i<9;++i){ e.A[i]=0.0f; e.C[i]=0.0f; e.J[i]=0.0f; }
  e.A[0]=e.A[4]=e.A[8]=1.0f;
  e.b[0]=e.b[1]=e.b[2]=0.0f; e.h[0]=e.h[1]=e.h[2]=0.0f;
  return e;
}
DEV void fe_store(const FE& e, float* g) {
#pragma unroll
  for (int i=0;i<9;++i) g[i]=e.A[i];
  g[9]=e.b[0]; g[10]=e.b[1]; g[11]=e.b[2];
#pragma unroll
  for (int i=0;i<9;++i) g[12+i]=e.C[i];
  g[21]=e.h[0]; g[22]=e.h[1]; g[23]=e.h[2];
#pragma unroll
  for (int i=0;i<9;++i) g[24+i]=e.J[i];
}
DEV FE fe_load(const float* g) {
  FE e;
#pragma unroll
  for (int i=0;i<9;++i) e.A[i]=g[i];
  e.b[0]=g[9]; e.b[1]=g[10]; e.b[2]=g[11];
#pragma unroll
  for (int i=0;i<9;++i) e.C[i]=g[12+i];
  e.h[0]=g[21]; e.h[1]=g[22]; e.h[2]=g[23];
#pragma unroll
  for (int i=0;i<9;++i) e.J[i]=g[24+i];
  return e;
}
DEV FE build_felem(const Model& M, float dt, float obsf, float rf, float Rf_, bool first) {
  FE E;
  float r = rf, R = Rf_;
  float g = (obsf > 0.5f) ? 1.0f : 0.0f;
  if (first) {
#pragma unroll
    for (int i=0;i<9;++i){ E.A[i]=0.0f; E.J[i]=0.0f; }
    E.h[0]=E.h[1]=E.h[2]=0.0f;
    float Pi[9]; pinf(M, Pi);
    float S = Pi[0] + R;
    float f = g / S;
    float K0=Pi[0]*f, K1=Pi[3]*f, K2=Pi[6]*f;
    E.b[0]=K0*r; E.b[1]=K1*r; E.b[2]=K2*r;
    E.C[0]=Pi[0]-S*K0*K0; E.C[1]=Pi[1]-S*K0*K1; E.C[2]=Pi[2]-S*K0*K2;
    E.C[3]=Pi[3]-S*K1*K0; E.C[4]=Pi[4]-S*K1*K1; E.C[5]=Pi[5]-S*K1*K2;
    E.C[6]=Pi[6]-S*K2*K0; E.C[7]=Pi[7]-S*K2*K1; E.C[8]=Pi[8]-S*K2*K2;
    return E;
  }
  float Am[9], Q[9]; make_AQ(M, dt, Am, Q);
  float S = Q[0] + R, iS = g / S;   // gated: obs=0 -> K=0, A=Am, C=Q, h=0, J=0
  float K0=Q[0]*iS, K1=Q[3]*iS, K2=Q[6]*iS;
#pragma unroll
  for (int j = 0; j < 3; ++j) {
    E.A[j]   = Am[j]   - K0*Am[j];
    E.A[3+j] = Am[3+j] - K1*Am[j];
    E.A[6+j] = Am[6+j] - K2*Am[j];
    E.C[j]   = Q[j]    - K0*Q[j];
    E.C[3+j] = Q[3+j]  - K1*Q[j];
    E.C[6+j] = Q[6+j]  - K2*Q[j];
  }
  E.b[0]=K0*r; E.b[1]=K1*r; E.b[2]=K2*r;
  float riS = r*iS;
  E.h[0]=Am[0]*riS; E.h[1]=Am[1]*riS; E.h[2]=Am[2]*riS;
#pragma unroll
  for (int i = 0; i < 3; ++i)
#pragma unroll
    for (int j = 0; j < 3; ++j)
      E.J[i*3+j] = Am[i]*Am[j]*iS;
  return E;
}
// compose: x earlier, y later
DEV FE fcompose(const FE& x, const FE& y) {
  const float *A1=x.A,*b1=x.b,*C1=x.C,*h1=x.h,*J1=x.J;
  const float *A2=y.A,*b2=y.b,*C2=y.C,*h2=y.h,*J2=y.J;
  FE o;
  float Mx[9]; mm(C1,J2,Mx); Mx[0]+=1.0f; Mx[4]+=1.0f; Mx[8]+=1.0f;
  float Mi[9]; inv3(Mx,Mi);
  float T1[9]; mm(A2,Mi,T1);
  mm(T1,A1,o.A);
  float u[3]; mv(C1,h2,u); u[0]+=b1[0]; u[1]+=b1[1]; u[2]+=b1[2];
  mv(T1,u,o.b); o.b[0]+=b2[0]; o.b[1]+=b2[1]; o.b[2]+=b2[2];
  float t2[9]; mm(T1,C1,t2);
  mmnt(t2,A2,o.C);
#pragma unroll
  for (int i=0;i<9;++i) o.C[i]+=C2[i];
  float tmp[9]; mm(Mi,A1,tmp);
  float w[3]; mv(J2,b1,w);
  w[0]=h2[0]-w[0]; w[1]=h2[1]-w[1]; w[2]=h2[2]-w[2];
  mtv(tmp,w,o.h); o.h[0]+=h1[0]; o.h[1]+=h1[1]; o.h[2]+=h1[2];
  float V[9]; mm(J2,A1,V);
  mtn(tmp,V,o.J);
#pragma unroll
  for (int i=0;i<9;++i) o.J[i]+=J1[i];
  symm(o.C); symm(o.J);
  return o;
}
// plain Kalman step (replay)
DEV void fstep(const Model& M, float dt, float obsf, float rf, float Rf_,
               float* m, float* P) {
  float A[9], Q[9]; make_AQ(M, dt, A, Q);
  float mp[3]; mv(A, m, mp);
  float W[9]; mmnt(P, A, W);      // P A^T
  float Pp[9]; mm(A, W, Pp);
#pragma unroll
  for (int i=0;i<9;++i) Pp[i]+=Q[i];
  float S = Pp[0] + Rf_;
  float f = (obsf > 0.5f) ? (1.0f/S) : 0.0f;
  float K0=Pp[0]*f, K1=Pp[3]*f, K2=Pp[6]*f;
  float v = rf - mp[0];
  m[0]=mp[0]+K0*v; m[1]=mp[1]+K1*v; m[2]=mp[2]+K2*v;
  P[0]=Pp[0]-S*K0*K0; P[1]=Pp[1]-S*K0*K1; P[2]=Pp[2]-S*K0*K2;
  P[3]=Pp[3]-S*K1*K0; P[4]=Pp[4]-S*K1*K1; P[5]=Pp[5]-S*K1*K2;
  P[6]=Pp[6]-S*K2*K0; P[7]=Pp[7]-S*K2*K1; P[8]=Pp[8]-S*K2*K2;
  symm(P);
}

// ---------------- smoother affine map: x_k = G x_{k+1} + c ; P_k = G P G^T + U ----------------
struct SE { float G[9]; float c[3]; float U[9]; };

DEV SE se_identity() {
  SE s;
#pragma unroll
  for (int i=0;i<9;++i){ s.G[i]=0.0f; s.U[i]=0.0f; }
  s.G[0]=s.G[4]=s.G[8]=1.0f;
  s.c[0]=s.c[1]=s.c[2]=0.0f;
  return s;
}
DEV void se_store(const SE& s, float* g) {   // packed-18
#pragma unroll
  for (int i=0;i<9;++i) g[i]=s.G[i];
  g[9]=s.c[0]; g[10]=s.c[1]; g[11]=s.c[2];
  g[12]=s.U[0]; g[13]=s.U[1]; g[14]=s.U[2]; g[15]=s.U[4]; g[16]=s.U[5]; g[17]=s.U[8];
}
DEV SE se_load(const float* g) {
  SE s;
#pragma unroll
  for (int i=0;i<9;++i) s.G[i]=g[i];
  s.c[0]=g[9]; s.c[1]=g[10]; s.c[2]=g[11];
  s.U[0]=g[12]; s.U[1]=g[13]; s.U[2]=g[14];
  s.U[3]=g[13]; s.U[4]=g[15]; s.U[5]=g[16];
  s.U[6]=g[14]; s.U[7]=g[16]; s.U[8]=g[17];
  return s;
}
// x earlier in time (applied LAST, since smoother runs backward)
DEV SE scompose(const SE& x, const SE& y) {
  SE o;
  mm(x.G, y.G, o.G);
  float t[3]; mv(x.G, y.c, t);
  o.c[0]=t[0]+x.c[0]; o.c[1]=t[1]+x.c[1]; o.c[2]=t[2]+x.c[2];
  float T[9]; mm(x.G, y.U, T);
  mmnt(T, x.G, o.U);
#pragma unroll
  for (int i=0;i<9;++i) o.U[i]+=x.U[i];
  symm(o.U);
  return o;
}
DEV void sapply(const SE& s, float* m, float* P) {
  float t[3]; mv(s.G, m, t);
  float T[9]; mm(s.G, P, T);
  float Pn[9]; mmnt(T, s.G, Pn);
  m[0]=t[0]+s.c[0]; m[1]=t[1]+s.c[1]; m[2]=t[2]+s.c[2];
#pragma unroll
  for (int i=0;i<9;++i) P[i]=Pn[i]+s.U[i];
  symm(P);
}
// build smoother element at global index k (requires k <= T_TOT-2)
DEV SE build_selem(const Model& M, const float4* pk, const float* mf, const float* Pf, int k) {
  float m[3] = { mf[k], mf[T_TOT+k], mf[2*T_TOT+k] };
  float p00=Pf[k], p01=Pf[T_TOT+k], p02=Pf[2*T_TOT+k],
        p11=Pf[3*T_TOT+k], p12=Pf[4*T_TOT+k], p22=Pf[5*T_TOT+k];
  float P[9] = { p00,p01,p02, p01,p11,p12, p02,p12,p22 };
  float dt = pk[k+1].x - pk[k].x;
  SE s;
  float A[9], Q[9]; make_AQ(M, dt, A, Q);
  float W[9]; mmnt(P, A, W);      // P A^T
  float Pp[9]; mm(A, W, Pp);
#pragma unroll
  for (int j=0;j<9;++j) Pp[j]+=Q[j];
  float Pi_[9]; inv3(Pp, Pi_);
  mm(W, Pi_, s.G);                 // G = P A^T Pp^-1
  float mp[3]; mv(A, m, mp);
  float gm[3]; mv(s.G, mp, gm);
  s.c[0]=m[0]-gm[0]; s.c[1]=m[1]-gm[1]; s.c[2]=m[2]-gm[2];
  float GW[9]; mmnt(s.G, W, GW);   // G Pp G^T
#pragma unroll
  for (int j=0;j<9;++j) s.U[j]=P[j]-GW[j];
  symm(s.U);
  return s;
}

// ================= kernels =================
// pk[k] = {time, residual, R, is_obs}  (natural order, CHUNK=1)
__global__ void k_merge(const float* __restrict__ times, const float* __restrict__ tstar,
                        const float* __restrict__ n1, const float* __restrict__ n2,
                        const float* __restrict__ mcp,
                        float4* pk, int* oix) {
  int g = blockIdx.x*blockDim.x + threadIdx.x;
  if (g >= T_TOT) return;
  float mc = mcp[0];
  if (g < N_TRAIN) {
    int i = g;
    float t = times[i];
    int lo = 0, hi = M_TEST;                 // count tstar strictly < t
    while (lo < hi) { int mid=(lo+hi)>>1; if (tstar[mid] < t) lo=mid+1; else hi=mid; }
    int p = i + lo;
    float s2 = n2[i];
    pk[p] = make_float4(t, n1[i]/s2 - mc, 1.0f/s2, 1.0f);
    oix[p] = -1;
  } else {
    int j = g - N_TRAIN;
    float t = tstar[j];
    int lo = 0, hi = N_TRAIN;                // count times <= t (stable: train first)
    while (lo < hi) { int mid=(lo+hi)>>1; if (times[mid] <= t) lo=mid+1; else hi=mid; }
    int p = j + lo;
    pk[p] = make_float4(t, 0.f, 1.f, 0.f);
    oix[p] = j;
  }
}

// F1: one element per thread, 64-wide in-wave inclusive scan.
__global__ __launch_bounds__(TPB, 3) void k_f1(
    const float* varp, const float* ellp, const float4* __restrict__ pk,
    float* tIncl, float* blkAgg) {
  __shared__ float lds[TPB*FE_S];
  int l = threadIdx.x, b = blockIdx.x;
  int t = b*TPB + l;
  Model M = make_model(varp, ellp);
  float4 q = pk[t];
  float dt = (t == 0) ? 0.0f : (q.x - pk[t-1].x);
  FE run = build_felem(M, dt, q.w, q.y, q.z, t == 0);
  fe_store(run, &lds[l*FE_S]);
  for (int d = 1; d < TPB; d <<= 1) {
    __syncthreads();
    FE oth; bool act = (l >= d);
    if (act) oth = fe_load(&lds[(l-d)*FE_S]);
    __syncthreads();
    if (act) { run = fcompose(oth, run); fe_store(run, &lds[l*FE_S]); }
  }
  fe_store(run, tIncl + t*FE_S);
  if (l == TPB-1) fe_store(run, blkAgg + b*FE_S);
}

// F2: one 512-thread block scans 3072 block aggregates (6 per thread).
__global__ __launch_bounds__(MIDT, 2) void k_f2(const float* __restrict__ blkAgg,
                                                float* blkPref) {
  __shared__ float lds[MIDT*FE_S];
  int j = threadIdx.x;
  FE run = fe_load(blkAgg + (MPT*j)*FE_S);
#pragma unroll
  for (int i = 1; i < MPT; ++i) run = fcompose(run, fe_load(blkAgg + (MPT*j+i)*FE_S));
  fe_store(run, &lds[j*FE_S]);
  for (int d = 1; d < MIDT; d <<= 1) {
    __syncthreads();
    FE oth; bool act = (j >= d);
    if (act) oth = fe_load(&lds[(j-d)*FE_S]);
    __syncthreads();
    if (act) { run = fcompose(oth, run); fe_store(run, &lds[j*FE_S]); }
  }
  __syncthreads();
  FE X = (j == 0) ? fe_identity() : fe_load(&lds[(j-1)*FE_S]);
  fe_store(X, blkPref + (MPT*j)*FE_S);
#pragma unroll
  for (int i = 0; i < MPT-1; ++i) {
    X = fcompose(X, fe_load(blkAgg + (MPT*j+i)*FE_S));
    fe_store(X, blkPref + (MPT*j+i+1)*FE_S);
  }
}

// F3: entry = blkPref[b] ∘ tIncl[t-1]; one fstep; store filtered state.
__global__ __launch_bounds__(TPB, 3) void k_f3(
    const float* varp, const float* ellp, const float4* __restrict__ pk,
    const float* __restrict__ tIncl, const float* __restrict__ blkPref,
    float* mf, float* Pf, float* xT) {
  int l = threadIdx.x, b = blockIdx.x;
  int t = b*TPB + l;
  Model M = make_model(varp, ellp);
  float m[3], P[9];
  if (t == 0) {
    m[0]=m[1]=m[2]=0.0f; pinf(M, P);
  } else {
    FE bp = fe_load(blkPref + b*FE_S);
    FE ent = (l == 0) ? bp : fcompose(bp, fe_load(tIncl + (t-1)*FE_S));
    m[0]=ent.b[0]; m[1]=ent.b[1]; m[2]=ent.b[2];
#pragma unroll
    for (int i=0;i<9;++i) P[i]=ent.C[i];
  }
  float4 q = pk[t];
  float dt = (t == 0) ? 0.0f : (q.x - pk[t-1].x);
  fstep(M, dt, q.w, q.y, q.z, m, P);
  mf[t]=m[0]; mf[T_TOT+t]=m[1]; mf[2*T_TOT+t]=m[2];
  Pf[t]=P[0]; Pf[T_TOT+t]=P[1]; Pf[2*T_TOT+t]=P[2];
  Pf[3*T_TOT+t]=P[4]; Pf[4*T_TOT+t]=P[5]; Pf[5*T_TOT+t]=P[8];
  if (t == T_TOT-1) {
    xT[0]=m[0]; xT[1]=m[1]; xT[2]=m[2];
    xT[3]=P[0]; xT[4]=P[1]; xT[5]=P[2];
    xT[6]=P[4]; xT[7]=P[5]; xT[8]=P[8];
  }
}

// S1: one smoother map per thread, 64-wide backward (suffix) scan.
__global__ __launch_bounds__(TPB, 3) void k_s1(
    const float* varp, const float* ellp, const float4* __restrict__ pk,
    const float* __restrict__ mf, const float* __restrict__ Pf,
    float* tSuf, float* blkAggS) {
  __shared__ float lds[TPB*SE_S];
  int l = threadIdx.x, b = blockIdx.x;
  int t = b*TPB + l;
  Model M = make_model(varp, ellp);
  SE Macc = (t <= T_TOT-2) ? build_selem(M, pk, mf, Pf, t) : se_identity();
  se_store(Macc, &lds[l*SE_S]);
  for (int d = 1; d < TPB; d <<= 1) {
    __syncthreads();
    SE oth; bool act = (l + d < TPB);
    if (act) oth = se_load(&lds[(l+d)*SE_S]);
    __syncthreads();
    if (act) { Macc = scompose(Macc, oth); se_store(Macc, &lds[l*SE_S]); }
  }
  se_store(Macc, tSuf + t*18);
  if (l == 0) se_store(Macc, blkAggS + b*18);
}

// S2: one 512-thread block backward-scans 3072 aggregates (6/thread);
// emits per-block EXIT state bExit[b] = smoothed state at first index of block b+1
// (for the last block: xT).
__global__ __launch_bounds__(MIDT, 2) void k_s2(const float* __restrict__ blkAggS,
                                                const float* __restrict__ xT,
                                                float* bExit) {
  __shared__ float lds[MIDT*SE_S];
  int j = threadIdx.x;
  SE a[MPT];
#pragma unroll
  for (int i = 0; i < MPT; ++i) a[i] = se_load(blkAggS + (MPT*j+i)*18);
  SE run = a[MPT-1];
#pragma unroll
  for (int i = MPT-2; i >= 0; --i) run = scompose(a[i], run);
  se_store(run, &lds[j*SE_S]);
  for (int d = 1; d < MIDT; d <<= 1) {
    __syncthreads();
    SE oth; bool act = (j + d < MIDT);
    if (act) oth = se_load(&lds[(j+d)*SE_S]);
    __syncthreads();
    if (act) { run = scompose(run, oth); se_store(run, &lds[j*SE_S]); }
  }
  __syncthreads();
  float m[3] = { xT[0], xT[1], xT[2] };
  float P[9] = { xT[3],xT[4],xT[5], xT[4],xT[6],xT[7], xT[5],xT[7],xT[8] };
  if (j < MIDT-1) {
    SE Sx = se_load(&lds[(j+1)*SE_S]);  // suffix of threads > j
    sapply(Sx, m, P);                   // -> exit of block MPT*j+MPT-1
  }                                      // j==MIDT-1: exit of last block is xT
  {
    float* o = bExit + (MPT*j+MPT-1)*9;
    o[0]=m[0];o[1]=m[1];o[2]=m[2];o[3]=P[0];o[4]=P[1];o[5]=P[2];o[6]=P[4];o[7]=P[5];o[8]=P[8];
  }
#pragma unroll
  for (int i = MPT-1; i >= 1; --i) {
    sapply(a[i], m, P);                 // exit of block MPT*j+i-1
    float* o = bExit + (MPT*j+i-1)*9;
    o[0]=m[0];o[1]=m[1];o[2]=m[2];o[3]=P[0];o[4]=P[1];o[5]=P[2];o[6]=P[4];o[7]=P[5];o[8]=P[8];
  }
}

// S3: x_{t+1} = tSuf[t+1](bExit[b]) (or bExit for l=63); apply own map; write output.
__global__ __launch_bounds__(TPB, 3) void k_s3(
    const float* varp, const float* ellp, const float* mcp,
    const float4* __restrict__ pk,
    const float* __restrict__ mf, const float* __restrict__ Pf,
    const float* __restrict__ tSuf, const float* __restrict__ bExit,
    const int* __restrict__ oix, float* out) {
  int l = threadIdx.x, b = blockIdx.x;
  int t = b*TPB + l;
  Model M = make_model(varp, ellp);
  float mc = mcp[0];
  const float* g = bExit + b*9;
  float m[3] = { g[0], g[1], g[2] };
  float P[9] = { g[3],g[4],g[5], g[4],g[6],g[7], g[5],g[7],g[8] };
  if (l < TPB-1) {
    SE s = se_load(tSuf + (t+1)*18);
    sapply(s, m, P);                  // -> x_{t+1}
  }
  if (t <= T_TOT-2) {
    SE e = build_selem(M, pk, mf, Pf, t);
    sapply(e, m, P);                  // -> x_t
  }                                   // t==T_TOT-1: (m,P) == xT == x_t already
  int j = oix[t];
  if (j >= 0) { out[j] = m[0] + mc; out[M_TEST + j] = fmaxf(P[0], 0.0f); }
}

extern "C" void kernel_launch(void* const* d_in, const int* in_sizes, int n_in,
                              void* d_out, int out_size, void* d_ws, size_t ws_size,
                              hipStream_t stream) {
  const float* times = (const float*)d_in[0];
  const float* tstar = (const float*)d_in[1];
  const float* n1    = (const float*)d_in[2];
  const float* n2    = (const float*)d_in[3];
  const float* varp  = (const float*)d_in[4];
  const float* ellp  = (const float*)d_in[5];
  const float* mcp   = (const float*)d_in[6];
  float* out = (float*)d_out;

  size_t off = 0;
  auto take = [&](size_t bytes) {
    char* p = (char*)d_ws + off;
    off += (bytes + 255) & ~(size_t)255;
    return (void*)p;
  };
  float4* pk    = (float4*)take(sizeof(float4) * T_TOT);
  int*    oix   = (int*)   take(sizeof(int)    * T_TOT);
  float*  mf    = (float*) take(sizeof(float)  * 3 * T_TOT);
  float*  Pf    = (float*) take(sizeof(float)  * 6 * T_TOT);
  float*  tIncl = (float*) take(sizeof(float)  * FE_S * T_TOT);
  float*  blkAgg= (float*) take(sizeof(float)  * FE_S * NBLK);
  float*  blkPref=(float*) take(sizeof(float)  * FE_S * NBLK);
  float*  tSuf  = (float*) take(sizeof(float)  * 18 * T_TOT);
  float*  blkAggS=(float*) take(sizeof(float)  * 18 * NBLK);
  float*  bExit = (float*) take(sizeof(float)  * 9  * NBLK);
  float*  xT    = (float*) take(sizeof(float)  * 9);
  (void)ws_size; (void)in_sizes; (void)n_in; (void)out_size;

  k_merge<<<(T_TOT+255)/256, 256, 0, stream>>>(times, tstar, n1, n2, mcp, pk, oix);
  k_f1   <<<NBLK, TPB, 0, stream>>>(varp, ellp, pk, tIncl, blkAgg);
  k_f2   <<<1, MIDT, 0, stream>>>(blkAgg, blkPref);
  k_f3   <<<NBLK, TPB, 0, stream>>>(varp, ellp, pk, tIncl, blkPref, mf, Pf, xT);
  k_s1   <<<NBLK, TPB, 0, stream>>>(varp, ellp, pk, mf, Pf, tSuf, blkAggS);
  k_s2   <<<1, MIDT, 0, stream>>>(blkAggS, xT, bExit);
  k_s3   <<<NBLK, TPB, 0, stream>>>(varp, ellp, mcp, pk, mf, Pf, tSuf, bExit, oix, out);
}

// Round 8
// 157.066 us; speedup vs baseline: 1.3891x; 1.3891x over previous
//
#include <hip/hip_runtime.h>
#include <math.h>

#define DEV __device__ __forceinline__

constexpr int N_TRAIN = 131072;
constexpr int M_TEST  = 65536;
constexpr int T_TOT   = N_TRAIN + M_TEST;  // 196608
constexpr int TPB     = 64;                // single-wave blocks
constexpr int NBLK    = T_TOT / TPB;       // 3072 level-1 blocks
constexpr int GRP     = 64;                // blocks per group (level-2 scan width)
constexpr int NGRP    = NBLK / GRP;        // 48 groups
constexpr int FE_S    = 33;                // FE LDS stride (floats)
constexpr int SE_S    = 19;                // SE LDS stride (18 + pad)

// ---------------- 3x3 helpers (row-major float[9]) ----------------
DEV void mm(const float* X, const float* Y, float* Z) {
#pragma unroll
  for (int i = 0; i < 3; ++i)
#pragma unroll
    for (int j = 0; j < 3; ++j)
      Z[i*3+j] = X[i*3]*Y[j] + X[i*3+1]*Y[3+j] + X[i*3+2]*Y[6+j];
}
DEV void mmnt(const float* X, const float* Y, float* Z) { // X * Y^T
#pragma unroll
  for (int i = 0; i < 3; ++i)
#pragma unroll
    for (int j = 0; j < 3; ++j)
      Z[i*3+j] = X[i*3]*Y[j*3] + X[i*3+1]*Y[j*3+1] + X[i*3+2]*Y[j*3+2];
}
DEV void mtn(const float* X, const float* Y, float* Z) { // X^T * Y
#pragma unroll
  for (int i = 0; i < 3; ++i)
#pragma unroll
    for (int j = 0; j < 3; ++j)
      Z[i*3+j] = X[i]*Y[j] + X[3+i]*Y[3+j] + X[6+i]*Y[6+j];
}
DEV void mv(const float* X, const float* v, float* w) {
#pragma unroll
  for (int i = 0; i < 3; ++i) w[i] = X[i*3]*v[0] + X[i*3+1]*v[1] + X[i*3+2]*v[2];
}
DEV void mtv(const float* X, const float* v, float* w) {
#pragma unroll
  for (int i = 0; i < 3; ++i) w[i] = X[i]*v[0] + X[3+i]*v[1] + X[6+i]*v[2];
}
// inverse with double cofactors (cancellation hedge); in/out fp32
DEV void inv3(const float* mf_, float* o) {
  double m0=mf_[0], m1=mf_[1], m2=mf_[2], m3=mf_[3], m4=mf_[4],
         m5=mf_[5], m6=mf_[6], m7=mf_[7], m8=mf_[8];
  double c00 = m4*m8 - m5*m7;
  double c10 = m5*m6 - m3*m8;
  double c20 = m3*m7 - m4*m6;
  double det = m0*c00 + m1*c10 + m2*c20;
  double id = 1.0 / det;
  o[0] = (float)(c00*id); o[1] = (float)((m2*m7-m1*m8)*id); o[2] = (float)((m1*m5-m2*m4)*id);
  o[3] = (float)(c10*id); o[4] = (float)((m0*m8-m2*m6)*id); o[5] = (float)((m2*m3-m0*m5)*id);
  o[6] = (float)(c20*id); o[7] = (float)((m1*m6-m0*m7)*id); o[8] = (float)((m0*m4-m1*m3)*id);
}
DEV void symm(float* P) {
  float a = 0.5f*(P[1]+P[3]), b = 0.5f*(P[2]+P[6]), c = 0.5f*(P[5]+P[7]);
  P[1]=P[3]=a; P[2]=P[6]=b; P[5]=P[7]=c;
}

// ---------------- model ----------------
struct Model { float lam, v, kap, l4; };
DEV Model make_model(const float* varp, const float* ellp) {
  Model M; M.v = varp[0];
  float ell = ellp[0];
  M.lam = sqrtf(5.0f) / ell;
  M.kap = M.lam * M.lam / 3.0f;
  float l2 = M.lam * M.lam;
  M.l4 = l2 * l2;
  return M;
}
DEV void pinf(const Model& M, float* P) {
  float vk = M.v * M.kap;
  P[0]=M.v; P[1]=0;  P[2]=-vk;
  P[3]=0;   P[4]=vk; P[5]=0;
  P[6]=-vk; P[7]=0;  P[8]=M.v*M.l4;
}
DEV void make_AQ(const Model& M, float dt, float* A, float* Q) {
  float lam = M.lam, l2 = lam*lam, l3 = l2*lam, l4 = M.l4;
  float e = __expf(-lam * dt);
  float h = 0.5f * dt * dt;
  A[0] = e*(1.0f + dt*lam + h*l2);
  A[1] = e*(dt + 2.0f*h*lam);
  A[2] = e*h;
  A[3] = e*(-h*l3);
  A[4] = e*(1.0f + dt*lam - 2.0f*h*l2);
  A[5] = e*(dt - h*lam);
  A[6] = e*(-dt*l3 + h*l4);
  A[7] = e*(-3.0f*dt*l2 + 2.0f*h*l3);
  A[8] = e*(1.0f - 2.0f*dt*lam + h*l2);
  float vk = M.v * M.kap, vl4 = M.v * M.l4;
  float B[9];  // A * Pinf
#pragma unroll
  for (int i = 0; i < 3; ++i) {
    B[i*3+0] =  A[i*3+0]*M.v - A[i*3+2]*vk;
    B[i*3+1] =  A[i*3+1]*vk;
    B[i*3+2] = -A[i*3+0]*vk  + A[i*3+2]*vl4;
  }
  float Pi[9]; pinf(M, Pi);
#pragma unroll
  for (int i = 0; i < 3; ++i)
#pragma unroll
    for (int j = 0; j < 3; ++j)
      Q[i*3+j] = Pi[i*3+j] - (B[i*3]*A[j*3] + B[i*3+1]*A[j*3+1] + B[i*3+2]*A[j*3+2]);
}

// ---------------- filter scan element ----------------
struct FE { float A[9]; float b[3]; float C[9]; float h[3]; float J[9]; };

DEV FE fe_identity() {
  FE e;
#pragma unroll
  for (int i=0;i<9;++i){ e.A[i]=0.0f; e.C[i]=0.0f; e.J[i]=0.0f; }
  e.A[0]=e.A[4]=e.A[8]=1.0f;
  e.b[0]=e.b[1]=e.b[2]=0.0f; e.h[0]=e.h[1]=e.h[2]=0.0f;
  return e;
}
DEV void fe_store(const FE& e, float* g) {          // contiguous 33
#pragma unroll
  for (int i=0;i<9;++i) g[i]=e.A[i];
  g[9]=e.b[0]; g[10]=e.b[1]; g[11]=e.b[2];
#pragma unroll
  for (int i=0;i<9;++i) g[12+i]=e.C[i];
  g[21]=e.h[0]; g[22]=e.h[1]; g[23]=e.h[2];
#pragma unroll
  for (int i=0;i<9;++i) g[24+i]=e.J[i];
}
DEV FE fe_load(const float* g) {
  FE e;
#pragma unroll
  for (int i=0;i<9;++i) e.A[i]=g[i];
  e.b[0]=g[9]; e.b[1]=g[10]; e.b[2]=g[11];
#pragma unroll
  for (int i=0;i<9;++i) e.C[i]=g[12+i];
  e.h[0]=g[21]; e.h[1]=g[22]; e.h[2]=g[23];
#pragma unroll
  for (int i=0;i<9;++i) e.J[i]=g[24+i];
  return e;
}
// transposed (component-major) global layout: g[comp*n + idx] -> lane-coalesced
DEV void fe_storeT(const FE& e, float* g, int idx, int n) {
#pragma unroll
  for (int i=0;i<9;++i) g[i*n+idx]=e.A[i];
#pragma unroll
  for (int i=0;i<3;++i) g[(9+i)*n+idx]=e.b[i];
#pragma unroll
  for (int i=0;i<9;++i) g[(12+i)*n+idx]=e.C[i];
#pragma unroll
  for (int i=0;i<3;++i) g[(21+i)*n+idx]=e.h[i];
#pragma unroll
  for (int i=0;i<9;++i) g[(24+i)*n+idx]=e.J[i];
}
DEV FE fe_loadT(const float* g, int idx, int n) {
  FE e;
#pragma unroll
  for (int i=0;i<9;++i) e.A[i]=g[i*n+idx];
#pragma unroll
  for (int i=0;i<3;++i) e.b[i]=g[(9+i)*n+idx];
#pragma unroll
  for (int i=0;i<9;++i) e.C[i]=g[(12+i)*n+idx];
#pragma unroll
  for (int i=0;i<3;++i) e.h[i]=g[(21+i)*n+idx];
#pragma unroll
  for (int i=0;i<9;++i) e.J[i]=g[(24+i)*n+idx];
  return e;
}
DEV FE build_felem(const Model& M, float dt, float obsf, float rf, float Rf_, bool first) {
  FE E;
  float r = rf, R = Rf_;
  float g = (obsf > 0.5f) ? 1.0f : 0.0f;
  if (first) {
#pragma unroll
    for (int i=0;i<9;++i){ E.A[i]=0.0f; E.J[i]=0.0f; }
    E.h[0]=E.h[1]=E.h[2]=0.0f;
    float Pi[9]; pinf(M, Pi);
    float S = Pi[0] + R;
    float f = g / S;
    float K0=Pi[0]*f, K1=Pi[3]*f, K2=Pi[6]*f;
    E.b[0]=K0*r; E.b[1]=K1*r; E.b[2]=K2*r;
    E.C[0]=Pi[0]-S*K0*K0; E.C[1]=Pi[1]-S*K0*K1; E.C[2]=Pi[2]-S*K0*K2;
    E.C[3]=Pi[3]-S*K1*K0; E.C[4]=Pi[4]-S*K1*K1; E.C[5]=Pi[5]-S*K1*K2;
    E.C[6]=Pi[6]-S*K2*K0; E.C[7]=Pi[7]-S*K2*K1; E.C[8]=Pi[8]-S*K2*K2;
    return E;
  }
  float Am[9], Q[9]; make_AQ(M, dt, Am, Q);
  float S = Q[0] + R, iS = g / S;   // gated: obs=0 -> K=0, A=Am, C=Q, h=0, J=0
  float K0=Q[0]*iS, K1=Q[3]*iS, K2=Q[6]*iS;
#pragma unroll
  for (int j = 0; j < 3; ++j) {
    E.A[j]   = Am[j]   - K0*Am[j];
    E.A[3+j] = Am[3+j] - K1*Am[j];
    E.A[6+j] = Am[6+j] - K2*Am[j];
    E.C[j]   = Q[j]    - K0*Q[j];
    E.C[3+j] = Q[3+j]  - K1*Q[j];
    E.C[6+j] = Q[6+j]  - K2*Q[j];
  }
  E.b[0]=K0*r; E.b[1]=K1*r; E.b[2]=K2*r;
  float riS = r*iS;
  E.h[0]=Am[0]*riS; E.h[1]=Am[1]*riS; E.h[2]=Am[2]*riS;
#pragma unroll
  for (int i = 0; i < 3; ++i)
#pragma unroll
    for (int j = 0; j < 3; ++j)
      E.J[i*3+j] = Am[i]*Am[j]*iS;
  return E;
}
// compose: x earlier, y later
DEV FE fcompose(const FE& x, const FE& y) {
  const float *A1=x.A,*b1=x.b,*C1=x.C,*h1=x.h,*J1=x.J;
  const float *A2=y.A,*b2=y.b,*C2=y.C,*h2=y.h,*J2=y.J;
  FE o;
  float Mx[9]; mm(C1,J2,Mx); Mx[0]+=1.0f; Mx[4]+=1.0f; Mx[8]+=1.0f;
  float Mi[9]; inv3(Mx,Mi);
  float T1[9]; mm(A2,Mi,T1);
  mm(T1,A1,o.A);
  float u[3]; mv(C1,h2,u); u[0]+=b1[0]; u[1]+=b1[1]; u[2]+=b1[2];
  mv(T1,u,o.b); o.b[0]+=b2[0]; o.b[1]+=b2[1]; o.b[2]+=b2[2];
  float t2[9]; mm(T1,C1,t2);
  mmnt(t2,A2,o.C);
#pragma unroll
  for (int i=0;i<9;++i) o.C[i]+=C2[i];
  float tmp[9]; mm(Mi,A1,tmp);
  float w[3]; mv(J2,b1,w);
  w[0]=h2[0]-w[0]; w[1]=h2[1]-w[1]; w[2]=h2[2]-w[2];
  mtv(tmp,w,o.h); o.h[0]+=h1[0]; o.h[1]+=h1[1]; o.h[2]+=h1[2];
  float V[9]; mm(J2,A1,V);
  mtn(tmp,V,o.J);
#pragma unroll
  for (int i=0;i<9;++i) o.J[i]+=J1[i];
  symm(o.C); symm(o.J);
  return o;
}
// plain Kalman step (replay)
DEV void fstep(const Model& M, float dt, float obsf, float rf, float Rf_,
               float* m, float* P) {
  float A[9], Q[9]; make_AQ(M, dt, A, Q);
  float mp[3]; mv(A, m, mp);
  float W[9]; mmnt(P, A, W);      // P A^T
  float Pp[9]; mm(A, W, Pp);
#pragma unroll
  for (int i=0;i<9;++i) Pp[i]+=Q[i];
  float S = Pp[0] + Rf_;
  float f = (obsf > 0.5f) ? (1.0f/S) : 0.0f;
  float K0=Pp[0]*f, K1=Pp[3]*f, K2=Pp[6]*f;
  float v = rf - mp[0];
  m[0]=mp[0]+K0*v; m[1]=mp[1]+K1*v; m[2]=mp[2]+K2*v;
  P[0]=Pp[0]-S*K0*K0; P[1]=Pp[1]-S*K0*K1; P[2]=Pp[2]-S*K0*K2;
  P[3]=Pp[3]-S*K1*K0; P[4]=Pp[4]-S*K1*K1; P[5]=Pp[5]-S*K1*K2;
  P[6]=Pp[6]-S*K2*K0; P[7]=Pp[7]-S*K2*K1; P[8]=Pp[8]-S*K2*K2;
  symm(P);
}

// ---------------- smoother affine map: x_k = G x_{k+1} + c ; P_k = G P G^T + U ----------------
struct SE { float G[9]; float c[3]; float U[9]; };

DEV SE se_identity() {
  SE s;
#pragma unroll
  for (int i=0;i<9;++i){ s.G[i]=0.0f; s.U[i]=0.0f; }
  s.G[0]=s.G[4]=s.G[8]=1.0f;
  s.c[0]=s.c[1]=s.c[2]=0.0f;
  return s;
}
DEV void se_store(const SE& s, float* g) {   // contiguous packed-18
#pragma unroll
  for (int i=0;i<9;++i) g[i]=s.G[i];
  g[9]=s.c[0]; g[10]=s.c[1]; g[11]=s.c[2];
  g[12]=s.U[0]; g[13]=s.U[1]; g[14]=s.U[2]; g[15]=s.U[4]; g[16]=s.U[5]; g[17]=s.U[8];
}
DEV SE se_load(const float* g) {
  SE s;
#pragma unroll
  for (int i=0;i<9;++i) s.G[i]=g[i];
  s.c[0]=g[9]; s.c[1]=g[10]; s.c[2]=g[11];
  s.U[0]=g[12]; s.U[1]=g[13]; s.U[2]=g[14];
  s.U[3]=g[13]; s.U[4]=g[15]; s.U[5]=g[16];
  s.U[6]=g[14]; s.U[7]=g[16]; s.U[8]=g[17];
  return s;
}
DEV void se_storeT(const SE& s, float* g, int idx, int n) {  // component-major
#pragma unroll
  for (int i=0;i<9;++i) g[i*n+idx]=s.G[i];
#pragma unroll
  for (int i=0;i<3;++i) g[(9+i)*n+idx]=s.c[i];
  g[12*n+idx]=s.U[0]; g[13*n+idx]=s.U[1]; g[14*n+idx]=s.U[2];
  g[15*n+idx]=s.U[4]; g[16*n+idx]=s.U[5]; g[17*n+idx]=s.U[8];
}
DEV SE se_loadT(const float* g, int idx, int n) {
  SE s;
#pragma unroll
  for (int i=0;i<9;++i) s.G[i]=g[i*n+idx];
#pragma unroll
  for (int i=0;i<3;++i) s.c[i]=g[(9+i)*n+idx];
  float u0=g[12*n+idx], u1=g[13*n+idx], u2=g[14*n+idx],
        u4=g[15*n+idx], u5=g[16*n+idx], u8=g[17*n+idx];
  s.U[0]=u0; s.U[1]=u1; s.U[2]=u2;
  s.U[3]=u1; s.U[4]=u4; s.U[5]=u5;
  s.U[6]=u2; s.U[7]=u5; s.U[8]=u8;
  return s;
}
// x earlier in time (applied LAST, since smoother runs backward)
DEV SE scompose(const SE& x, const SE& y) {
  SE o;
  mm(x.G, y.G, o.G);
  float t[3]; mv(x.G, y.c, t);
  o.c[0]=t[0]+x.c[0]; o.c[1]=t[1]+x.c[1]; o.c[2]=t[2]+x.c[2];
  float T[9]; mm(x.G, y.U, T);
  mmnt(T, x.G, o.U);
#pragma unroll
  for (int i=0;i<9;++i) o.U[i]+=x.U[i];
  symm(o.U);
  return o;
}
DEV void sapply(const SE& s, float* m, float* P) {
  float t[3]; mv(s.G, m, t);
  float T[9]; mm(s.G, P, T);
  float Pn[9]; mmnt(T, s.G, Pn);
  m[0]=t[0]+s.c[0]; m[1]=t[1]+s.c[1]; m[2]=t[2]+s.c[2];
#pragma unroll
  for (int i=0;i<9;++i) P[i]=Pn[i]+s.U[i];
  symm(P);
}
// build smoother element at global index k (requires k <= T_TOT-2)
DEV SE build_selem(const Model& M, const float4* pk, const float* mf, const float* Pf, int k) {
  float m[3] = { mf[k], mf[T_TOT+k], mf[2*T_TOT+k] };
  float p00=Pf[k], p01=Pf[T_TOT+k], p02=Pf[2*T_TOT+k],
        p11=Pf[3*T_TOT+k], p12=Pf[4*T_TOT+k], p22=Pf[5*T_TOT+k];
  float P[9] = { p00,p01,p02, p01,p11,p12, p02,p12,p22 };
  float dt = pk[k+1].x - pk[k].x;
  SE s;
  float A[9], Q[9]; make_AQ(M, dt, A, Q);
  float W[9]; mmnt(P, A, W);      // P A^T
  float Pp[9]; mm(A, W, Pp);
#pragma unroll
  for (int j=0;j<9;++j) Pp[j]+=Q[j];
  float Pi_[9]; inv3(Pp, Pi_);
  mm(W, Pi_, s.G);                 // G = P A^T Pp^-1
  float mp[3]; mv(A, m, mp);
  float gm[3]; mv(s.G, mp, gm);
  s.c[0]=m[0]-gm[0]; s.c[1]=m[1]-gm[1]; s.c[2]=m[2]-gm[2];
  float GW[9]; mmnt(s.G, W, GW);   // G Pp G^T
#pragma unroll
  for (int j=0;j<9;++j) s.U[j]=P[j]-GW[j];
  symm(s.U);
  return s;
}

// ================= kernels =================
// pk[k] = {time, residual, R, is_obs}  (natural order)
__global__ void k_merge(const float* __restrict__ times, const float* __restrict__ tstar,
                        const float* __restrict__ n1, const float* __restrict__ n2,
                        const float* __restrict__ mcp,
                        float4* pk, int* oix) {
  int g = blockIdx.x*blockDim.x + threadIdx.x;
  if (g >= T_TOT) return;
  float mc = mcp[0];
  if (g < N_TRAIN) {
    int i = g;
    float t = times[i];
    int lo = 0, hi = M_TEST;                 // count tstar strictly < t
    while (lo < hi) { int mid=(lo+hi)>>1; if (tstar[mid] < t) lo=mid+1; else hi=mid; }
    int p = i + lo;
    float s2 = n2[i];
    pk[p] = make_float4(t, n1[i]/s2 - mc, 1.0f/s2, 1.0f);
    oix[p] = -1;
  } else {
    int j = g - N_TRAIN;
    float t = tstar[j];
    int lo = 0, hi = N_TRAIN;                // count times <= t (stable: train first)
    while (lo < hi) { int mid=(lo+hi)>>1; if (times[mid] <= t) lo=mid+1; else hi=mid; }
    int p = j + lo;
    pk[p] = make_float4(t, 0.f, 1.f, 0.f);
    oix[p] = j;
  }
}

// F1: one element per thread, 64-wide in-wave inclusive scan.
__global__ __launch_bounds__(TPB, 2) void k_f1(
    const float* varp, const float* ellp, const float4* __restrict__ pk,
    float* tIncl, float* blkAgg) {
  __shared__ float lds[TPB*FE_S];
  int l = threadIdx.x, b = blockIdx.x;
  int t = b*TPB + l;
  Model M = make_model(varp, ellp);
  float4 q = pk[t];
  float dt = (t == 0) ? 0.0f : (q.x - pk[t-1].x);
  FE run = build_felem(M, dt, q.w, q.y, q.z, t == 0);
  fe_store(run, &lds[l*FE_S]);
  for (int d = 1; d < TPB; d <<= 1) {
    __syncthreads();
    FE oth; bool act = (l >= d);
    if (act) oth = fe_load(&lds[(l-d)*FE_S]);
    __syncthreads();
    if (act) { run = fcompose(oth, run); fe_store(run, &lds[l*FE_S]); }
  }
  fe_storeT(run, tIncl, t, T_TOT);
  if (l == TPB-1) fe_storeT(run, blkAgg, b, NBLK);
}

// F2a: 48 blocks x 64; wave-scan 64 block aggregates each -> blkIncl2, group agg.
__global__ __launch_bounds__(TPB, 2) void k_f2a(const float* __restrict__ blkAgg,
                                                float* blkIncl2, float* grpAgg) {
  __shared__ float lds[TPB*FE_S];
  int l = threadIdx.x, gb = blockIdx.x;
  int b = gb*GRP + l;
  FE run = fe_loadT(blkAgg, b, NBLK);
  fe_store(run, &lds[l*FE_S]);
  for (int d = 1; d < TPB; d <<= 1) {
    __syncthreads();
    FE oth; bool act = (l >= d);
    if (act) oth = fe_load(&lds[(l-d)*FE_S]);
    __syncthreads();
    if (act) { run = fcompose(oth, run); fe_store(run, &lds[l*FE_S]); }
  }
  fe_storeT(run, blkIncl2, b, NBLK);
  if (l == GRP-1) fe_store(run, grpAgg + gb*FE_S);
}

// F2b: one 64-thread block scans the 48 group aggregates -> exclusive group prefix.
__global__ __launch_bounds__(TPB, 2) void k_f2b(const float* __restrict__ grpAgg,
                                                float* grpPref) {
  __shared__ float lds[TPB*FE_S];
  int j = threadIdx.x;
  FE run = (j < NGRP) ? fe_load(grpAgg + j*FE_S) : fe_identity();
  fe_store(run, &lds[j*FE_S]);
  for (int d = 1; d < TPB; d <<= 1) {
    __syncthreads();
    FE oth; bool act = (j >= d);
    if (act) oth = fe_load(&lds[(j-d)*FE_S]);
    __syncthreads();
    if (act) { run = fcompose(oth, run); fe_store(run, &lds[j*FE_S]); }
  }
  __syncthreads();
  if (j < NGRP) {
    FE X = (j == 0) ? fe_identity() : fe_load(&lds[(j-1)*FE_S]);
    fe_store(X, grpPref + j*FE_S);
  }
}

// F3: entry = grpPref[g] ∘ blkIncl2[b-1] ∘ tIncl[t-1]; one fstep; store state.
__global__ __launch_bounds__(TPB, 2) void k_f3(
    const float* varp, const float* ellp, const float4* __restrict__ pk,
    const float* __restrict__ tIncl, const float* __restrict__ blkIncl2,
    const float* __restrict__ grpPref,
    float* mf, float* Pf, float* xT) {
  int l = threadIdx.x, b = blockIdx.x;
  int t = b*TPB + l;
  int g = b >> 6, lb = b & (GRP-1);
  Model M = make_model(varp, ellp);
  float m[3], P[9];
  if (t == 0) {
    m[0]=m[1]=m[2]=0.0f; pinf(M, P);
  } else {
    FE gp = fe_load(grpPref + g*FE_S);                         // broadcast
    FE entB = (lb == 0) ? gp : fcompose(gp, fe_loadT(blkIncl2, b-1, NBLK));
    FE ent  = (l == 0) ? entB : fcompose(entB, fe_loadT(tIncl, t-1, T_TOT));
    m[0]=ent.b[0]; m[1]=ent.b[1]; m[2]=ent.b[2];
#pragma unroll
    for (int i=0;i<9;++i) P[i]=ent.C[i];
  }
  float4 q = pk[t];
  float dt = (t == 0) ? 0.0f : (q.x - pk[t-1].x);
  fstep(M, dt, q.w, q.y, q.z, m, P);
  mf[t]=m[0]; mf[T_TOT+t]=m[1]; mf[2*T_TOT+t]=m[2];
  Pf[t]=P[0]; Pf[T_TOT+t]=P[1]; Pf[2*T_TOT+t]=P[2];
  Pf[3*T_TOT+t]=P[4]; Pf[4*T_TOT+t]=P[5]; Pf[5*T_TOT+t]=P[8];
  if (t == T_TOT-1) {
    xT[0]=m[0]; xT[1]=m[1]; xT[2]=m[2];
    xT[3]=P[0]; xT[4]=P[1]; xT[5]=P[2];
    xT[6]=P[4]; xT[7]=P[5]; xT[8]=P[8];
  }
}

// S1: one smoother map per thread, 64-wide backward (suffix) scan.
__global__ __launch_bounds__(TPB, 2) void k_s1(
    const float* varp, const float* ellp, const float4* __restrict__ pk,
    const float* __restrict__ mf, const float* __restrict__ Pf,
    float* tSuf, float* blkAggS) {
  __shared__ float lds[TPB*SE_S];
  int l = threadIdx.x, b = blockIdx.x;
  int t = b*TPB + l;
  Model M = make_model(varp, ellp);
  SE Macc = (t <= T_TOT-2) ? build_selem(M, pk, mf, Pf, t) : se_identity();
  se_store(Macc, &lds[l*SE_S]);
  for (int d = 1; d < TPB; d <<= 1) {
    __syncthreads();
    SE oth; bool act = (l + d < TPB);
    if (act) oth = se_load(&lds[(l+d)*SE_S]);
    __syncthreads();
    if (act) { Macc = scompose(Macc, oth); se_store(Macc, &lds[l*SE_S]); }
  }
  se_storeT(Macc, tSuf, t, T_TOT);
  if (l == 0) se_storeT(Macc, blkAggS, b, NBLK);
}

// S2a: 48 blocks x 64; backward wave-scan of block aggregates -> blkSuf2, group agg.
__global__ __launch_bounds__(TPB, 2) void k_s2a(const float* __restrict__ blkAggS,
                                                float* blkSuf2, float* grpAggS) {
  __shared__ float lds[TPB*SE_S];
  int l = threadIdx.x, gb = blockIdx.x;
  int b = gb*GRP + l;
  SE run = se_loadT(blkAggS, b, NBLK);
  se_store(run, &lds[l*SE_S]);
  for (int d = 1; d < TPB; d <<= 1) {
    __syncthreads();
    SE oth; bool act = (l + d < TPB);
    if (act) oth = se_load(&lds[(l+d)*SE_S]);
    __syncthreads();
    if (act) { run = scompose(run, oth); se_store(run, &lds[l*SE_S]); }
  }
  se_storeT(run, blkSuf2, b, NBLK);
  if (l == 0) se_store(run, grpAggS + gb*18);
}

// S2b: one 64-thread block backward-scans 48 group aggregates -> gExit[g] =
// smoothed state at first index of group g+1 (last group: xT).
__global__ __launch_bounds__(TPB, 2) void k_s2b(const float* __restrict__ grpAggS,
                                                const float* __restrict__ xT,
                                                float* gExit) {
  __shared__ float lds[TPB*SE_S];
  int j = threadIdx.x;
  SE run = (j < NGRP) ? se_load(grpAggS + j*18) : se_identity();
  se_store(run, &lds[j*SE_S]);
  for (int d = 1; d < TPB; d <<= 1) {
    __syncthreads();
    SE oth; bool act = (j + d < TPB);
    if (act) oth = se_load(&lds[(j+d)*SE_S]);
    __syncthreads();
    if (act) { run = scompose(run, oth); se_store(run, &lds[j*SE_S]); }
  }
  __syncthreads();
  if (j < NGRP) {
    float m[3] = { xT[0], xT[1], xT[2] };
    float P[9] = { xT[3],xT[4],xT[5], xT[4],xT[6],xT[7], xT[5],xT[7],xT[8] };
    if (j < NGRP-1) {
      SE Sx = se_load(&lds[(j+1)*SE_S]);  // suffix of groups j+1..NGRP-1
      sapply(Sx, m, P);
    }
    float* o = gExit + j*9;
    o[0]=m[0];o[1]=m[1];o[2]=m[2];o[3]=P[0];o[4]=P[1];o[5]=P[2];o[6]=P[4];o[7]=P[5];o[8]=P[8];
  }
}

// S3: gExit[g] -> (blkSuf2[b+1]) -> (tSuf[t+1]) -> own map; write output.
__global__ __launch_bounds__(TPB, 2) void k_s3(
    const float* varp, const float* ellp, const float* mcp,
    const float4* __restrict__ pk,
    const float* __restrict__ mf, const float* __restrict__ Pf,
    const float* __restrict__ tSuf, const float* __restrict__ blkSuf2,
    const float* __restrict__ gExit,
    const int* __restrict__ oix, float* out) {
  int l = threadIdx.x, b = blockIdx.x;
  int t = b*TPB + l;
  int g = b >> 6, lb = b & (GRP-1);
  Model M = make_model(varp, ellp);
  float mc = mcp[0];
  const float* ge = gExit + g*9;
  float m[3] = { ge[0], ge[1], ge[2] };
  float P[9] = { ge[3],ge[4],ge[5], ge[4],ge[6],ge[7], ge[5],ge[7],ge[8] };
  if (lb < GRP-1) {                  // -> state at first index of block b+1
    SE s = se_loadT(blkSuf2, b+1, NBLK);
    sapply(s, m, P);
  }
  if (l < TPB-1) {                   // -> x_{t+1}
    SE s = se_loadT(tSuf, t+1, T_TOT);
    sapply(s, m, P);
  }
  if (t <= T_TOT-2) {                // -> x_t
    SE e = build_selem(M, pk, mf, Pf, t);
    sapply(e, m, P);
  }                                  // t==T_TOT-1: (m,P) == xT already
  int j = oix[t];
  if (j >= 0) { out[j] = m[0] + mc; out[M_TEST + j] = fmaxf(P[0], 0.0f); }
}

extern "C" void kernel_launch(void* const* d_in, const int* in_sizes, int n_in,
                              void* d_out, int out_size, void* d_ws, size_t ws_size,
                              hipStream_t stream) {
  const float* times = (const float*)d_in[0];
  const float* tstar = (const float*)d_in[1];
  const float* n1    = (const float*)d_in[2];
  const float* n2    = (const float*)d_in[3];
  const float* varp  = (const float*)d_in[4];
  const float* ellp  = (const float*)d_in[5];
  const float* mcp   = (const float*)d_in[6];
  float* out = (float*)d_out;

  size_t off = 0;
  auto take = [&](size_t bytes) {
    char* p = (char*)d_ws + off;
    off += (bytes + 255) & ~(size_t)255;
    return (void*)p;
  };
  float4* pk     = (float4*)take(sizeof(float4) * T_TOT);
  int*    oix    = (int*)   take(sizeof(int)    * T_TOT);
  float*  mf     = (float*) take(sizeof(float)  * 3 * T_TOT);
  float*  Pf     = (float*) take(sizeof(float)  * 6 * T_TOT);
  float*  tIncl  = (float*) take(sizeof(float)  * FE_S * T_TOT);
  float*  blkAgg = (float*) take(sizeof(float)  * FE_S * NBLK);
  float*  blkIncl2=(float*) take(sizeof(float)  * FE_S * NBLK);
  float*  grpAgg = (float*) take(sizeof(float)  * FE_S * NGRP);
  float*  grpPref= (float*) take(sizeof(float)  * FE_S * NGRP);
  float*  tSuf   = (float*) take(sizeof(float)  * 18 * T_TOT);
  float*  blkAggS= (float*) take(sizeof(float)  * 18 * NBLK);
  float*  blkSuf2= (float*) take(sizeof(float)  * 18 * NBLK);
  float*  grpAggS= (float*) take(sizeof(float)  * 18 * NGRP);
  float*  gExit  = (float*) take(sizeof(float)  * 9  * NGRP);
  float*  xT     = (float*) take(sizeof(float)  * 9);
  (void)ws_size; (void)in_sizes; (void)n_in; (void)out_size;

  k_merge<<<(T_TOT+255)/256, 256, 0, stream>>>(times, tstar, n1, n2, mcp, pk, oix);
  k_f1   <<<NBLK, TPB, 0, stream>>>(varp, ellp, pk, tIncl, blkAgg);
  k_f2a  <<<NGRP, TPB, 0, stream>>>(blkAgg, blkIncl2, grpAgg);
  k_f2b  <<<1, TPB, 0, stream>>>(grpAgg, grpPref);
  k_f3   <<<NBLK, TPB, 0, stream>>>(varp, ellp, pk, tIncl, blkIncl2, grpPref, mf, Pf, xT);
  k_s1   <<<NBLK, TPB, 0, stream>>>(varp, ellp, pk, mf, Pf, tSuf, blkAggS);
  k_s2a  <<<NGRP, TPB, 0, stream>>>(blkAggS, blkSuf2, grpAggS);
  k_s2b  <<<1, TPB, 0, stream>>>(grpAggS, xT, gExit);
  k_s3   <<<NBLK, TPB, 0, stream>>>(varp, ellp, mcp, pk, mf, Pf, tSuf, blkSuf2, gExit, oix, out);
}

// Round 10
// 150.526 us; speedup vs baseline: 1.4494x; 1.0435x over previous
//
#include <hip/hip_runtime.h>
#include <math.h>

#define DEV __device__ __forceinline__

constexpr int N_TRAIN = 131072;
constexpr int M_TEST  = 65536;
constexpr int T_TOT   = N_TRAIN + M_TEST;  // 196608
constexpr int TPB     = 64;                // single-wave blocks
constexpr int NBLK    = T_TOT / TPB;       // 3072 level-1 blocks
constexpr int GRP     = 64;                // blocks per group (level-2 scan width)
constexpr int NGRP    = NBLK / GRP;        // 48 groups
constexpr int FE_S    = 33;                // FE record size (floats)

// ---------------- 3x3 helpers (row-major float[9]) ----------------
DEV void mm(const float* X, const float* Y, float* Z) {
#pragma unroll
  for (int i = 0; i < 3; ++i)
#pragma unroll
    for (int j = 0; j < 3; ++j)
      Z[i*3+j] = X[i*3]*Y[j] + X[i*3+1]*Y[3+j] + X[i*3+2]*Y[6+j];
}
DEV void mmnt(const float* X, const float* Y, float* Z) { // X * Y^T
#pragma unroll
  for (int i = 0; i < 3; ++i)
#pragma unroll
    for (int j = 0; j < 3; ++j)
      Z[i*3+j] = X[i*3]*Y[j*3] + X[i*3+1]*Y[j*3+1] + X[i*3+2]*Y[j*3+2];
}
DEV void mtn(const float* X, const float* Y, float* Z) { // X^T * Y
#pragma unroll
  for (int i = 0; i < 3; ++i)
#pragma unroll
    for (int j = 0; j < 3; ++j)
      Z[i*3+j] = X[i]*Y[j] + X[3+i]*Y[3+j] + X[6+i]*Y[6+j];
}
DEV void mv(const float* X, const float* v, float* w) {
#pragma unroll
  for (int i = 0; i < 3; ++i) w[i] = X[i*3]*v[0] + X[i*3+1]*v[1] + X[i*3+2]*v[2];
}
DEV void mtv(const float* X, const float* v, float* w) {
#pragma unroll
  for (int i = 0; i < 3; ++i) w[i] = X[i]*v[0] + X[3+i]*v[1] + X[6+i]*v[2];
}
// inverse with double cofactors (cancellation hedge); in/out fp32
DEV void inv3(const float* mf_, float* o) {
  double m0=mf_[0], m1=mf_[1], m2=mf_[2], m3=mf_[3], m4=mf_[4],
         m5=mf_[5], m6=mf_[6], m7=mf_[7], m8=mf_[8];
  double c00 = m4*m8 - m5*m7;
  double c10 = m5*m6 - m3*m8;
  double c20 = m3*m7 - m4*m6;
  double det = m0*c00 + m1*c10 + m2*c20;
  double id = 1.0 / det;
  o[0] = (float)(c00*id); o[1] = (float)((m2*m7-m1*m8)*id); o[2] = (float)((m1*m5-m2*m4)*id);
  o[3] = (float)(c10*id); o[4] = (float)((m0*m8-m2*m6)*id); o[5] = (float)((m2*m3-m0*m5)*id);
  o[6] = (float)(c20*id); o[7] = (float)((m1*m6-m0*m7)*id); o[8] = (float)((m0*m4-m1*m3)*id);
}
DEV void symm(float* P) {
  float a = 0.5f*(P[1]+P[3]), b = 0.5f*(P[2]+P[6]), c = 0.5f*(P[5]+P[7]);
  P[1]=P[3]=a; P[2]=P[6]=b; P[5]=P[7]=c;
}

// ---------------- model ----------------
struct Model { float lam, v, kap, l4; };
DEV Model make_model(const float* varp, const float* ellp) {
  Model M; M.v = varp[0];
  float ell = ellp[0];
  M.lam = sqrtf(5.0f) / ell;
  M.kap = M.lam * M.lam / 3.0f;
  float l2 = M.lam * M.lam;
  M.l4 = l2 * l2;
  return M;
}
DEV void pinf(const Model& M, float* P) {
  float vk = M.v * M.kap;
  P[0]=M.v; P[1]=0;  P[2]=-vk;
  P[3]=0;   P[4]=vk; P[5]=0;
  P[6]=-vk; P[7]=0;  P[8]=M.v*M.l4;
}
DEV void make_AQ(const Model& M, float dt, float* A, float* Q) {
  float lam = M.lam, l2 = lam*lam, l3 = l2*lam, l4 = M.l4;
  float e = __expf(-lam * dt);
  float h = 0.5f * dt * dt;
  A[0] = e*(1.0f + dt*lam + h*l2);
  A[1] = e*(dt + 2.0f*h*lam);
  A[2] = e*h;
  A[3] = e*(-h*l3);
  A[4] = e*(1.0f + dt*lam - 2.0f*h*l2);
  A[5] = e*(dt - h*lam);
  A[6] = e*(-dt*l3 + h*l4);
  A[7] = e*(-3.0f*dt*l2 + 2.0f*h*l3);
  A[8] = e*(1.0f - 2.0f*dt*lam + h*l2);
  float vk = M.v * M.kap, vl4 = M.v * M.l4;
  float B[9];  // A * Pinf
#pragma unroll
  for (int i = 0; i < 3; ++i) {
    B[i*3+0] =  A[i*3+0]*M.v - A[i*3+2]*vk;
    B[i*3+1] =  A[i*3+1]*vk;
    B[i*3+2] = -A[i*3+0]*vk  + A[i*3+2]*vl4;
  }
  float Pi[9]; pinf(M, Pi);
#pragma unroll
  for (int i = 0; i < 3; ++i)
#pragma unroll
    for (int j = 0; j < 3; ++j)
      Q[i*3+j] = Pi[i*3+j] - (B[i*3]*A[j*3] + B[i*3+1]*A[j*3+1] + B[i*3+2]*A[j*3+2]);
}

// ---------------- filter scan element ----------------
struct FE { float A[9]; float b[3]; float C[9]; float h[3]; float J[9]; };

DEV FE fe_identity() {
  FE e;
#pragma unroll
  for (int i=0;i<9;++i){ e.A[i]=0.0f; e.C[i]=0.0f; e.J[i]=0.0f; }
  e.A[0]=e.A[4]=e.A[8]=1.0f;
  e.b[0]=e.b[1]=e.b[2]=0.0f; e.h[0]=e.h[1]=e.h[2]=0.0f;
  return e;
}
DEV void fe_store(const FE& e, float* g) {          // contiguous 33
#pragma unroll
  for (int i=0;i<9;++i) g[i]=e.A[i];
  g[9]=e.b[0]; g[10]=e.b[1]; g[11]=e.b[2];
#pragma unroll
  for (int i=0;i<9;++i) g[12+i]=e.C[i];
  g[21]=e.h[0]; g[22]=e.h[1]; g[23]=e.h[2];
#pragma unroll
  for (int i=0;i<9;++i) g[24+i]=e.J[i];
}
DEV FE fe_load(const float* g) {
  FE e;
#pragma unroll
  for (int i=0;i<9;++i) e.A[i]=g[i];
  e.b[0]=g[9]; e.b[1]=g[10]; e.b[2]=g[11];
#pragma unroll
  for (int i=0;i<9;++i) e.C[i]=g[12+i];
  e.h[0]=g[21]; e.h[1]=g[22]; e.h[2]=g[23];
#pragma unroll
  for (int i=0;i<9;++i) e.J[i]=g[24+i];
  return e;
}
// transposed (component-major) global layout: g[comp*n + idx] -> lane-coalesced
DEV void fe_storeT(const FE& e, float* g, int idx, int n) {
#pragma unroll
  for (int i=0;i<9;++i) g[i*n+idx]=e.A[i];
#pragma unroll
  for (int i=0;i<3;++i) g[(9+i)*n+idx]=e.b[i];
#pragma unroll
  for (int i=0;i<9;++i) g[(12+i)*n+idx]=e.C[i];
#pragma unroll
  for (int i=0;i<3;++i) g[(21+i)*n+idx]=e.h[i];
#pragma unroll
  for (int i=0;i<9;++i) g[(24+i)*n+idx]=e.J[i];
}
DEV FE fe_loadT(const float* g, int idx, int n) {
  FE e;
#pragma unroll
  for (int i=0;i<9;++i) e.A[i]=g[i*n+idx];
#pragma unroll
  for (int i=0;i<3;++i) e.b[i]=g[(9+i)*n+idx];
#pragma unroll
  for (int i=0;i<9;++i) e.C[i]=g[(12+i)*n+idx];
#pragma unroll
  for (int i=0;i<3;++i) e.h[i]=g[(21+i)*n+idx];
#pragma unroll
  for (int i=0;i<9;++i) e.J[i]=g[(24+i)*n+idx];
  return e;
}
// wave shuffle of a whole FE (lane l gets lane l-d's value; garbage for l<d, guarded)
DEV FE fe_shfl_up(const FE& e, int d) {
  FE o;
#pragma unroll
  for (int i=0;i<9;++i) o.A[i]=__shfl_up(e.A[i], d, 64);
#pragma unroll
  for (int i=0;i<3;++i) o.b[i]=__shfl_up(e.b[i], d, 64);
#pragma unroll
  for (int i=0;i<9;++i) o.C[i]=__shfl_up(e.C[i], d, 64);
#pragma unroll
  for (int i=0;i<3;++i) o.h[i]=__shfl_up(e.h[i], d, 64);
#pragma unroll
  for (int i=0;i<9;++i) o.J[i]=__shfl_up(e.J[i], d, 64);
  return o;
}
DEV FE build_felem(const Model& M, float dt, float obsf, float rf, float Rf_, bool first) {
  FE E;
  float r = rf, R = Rf_;
  float g = (obsf > 0.5f) ? 1.0f : 0.0f;
  if (first) {
#pragma unroll
    for (int i=0;i<9;++i){ E.A[i]=0.0f; E.J[i]=0.0f; }
    E.h[0]=E.h[1]=E.h[2]=0.0f;
    float Pi[9]; pinf(M, Pi);
    float S = Pi[0] + R;
    float f = g / S;
    float K0=Pi[0]*f, K1=Pi[3]*f, K2=Pi[6]*f;
    E.b[0]=K0*r; E.b[1]=K1*r; E.b[2]=K2*r;
    E.C[0]=Pi[0]-S*K0*K0; E.C[1]=Pi[1]-S*K0*K1; E.C[2]=Pi[2]-S*K0*K2;
    E.C[3]=Pi[3]-S*K1*K0; E.C[4]=Pi[4]-S*K1*K1; E.C[5]=Pi[5]-S*K1*K2;
    E.C[6]=Pi[6]-S*K2*K0; E.C[7]=Pi[7]-S*K2*K1; E.C[8]=Pi[8]-S*K2*K2;
    return E;
  }
  float Am[9], Q[9]; make_AQ(M, dt, Am, Q);
  float S = Q[0] + R, iS = g / S;   // gated: obs=0 -> K=0, A=Am, C=Q, h=0, J=0
  float K0=Q[0]*iS, K1=Q[3]*iS, K2=Q[6]*iS;
#pragma unroll
  for (int j = 0; j < 3; ++j) {
    E.A[j]   = Am[j]   - K0*Am[j];
    E.A[3+j] = Am[3+j] - K1*Am[j];
    E.A[6+j] = Am[6+j] - K2*Am[j];
    E.C[j]   = Q[j]    - K0*Q[j];
    E.C[3+j] = Q[3+j]  - K1*Q[j];
    E.C[6+j] = Q[6+j]  - K2*Q[j];
  }
  E.b[0]=K0*r; E.b[1]=K1*r; E.b[2]=K2*r;
  float riS = r*iS;
  E.h[0]=Am[0]*riS; E.h[1]=Am[1]*riS; E.h[2]=Am[2]*riS;
#pragma unroll
  for (int i = 0; i < 3; ++i)
#pragma unroll
    for (int j = 0; j < 3; ++j)
      E.J[i*3+j] = Am[i]*Am[j]*iS;
  return E;
}
// compose: x earlier, y later
DEV FE fcompose(const FE& x, const FE& y) {
  const float *A1=x.A,*b1=x.b,*C1=x.C,*h1=x.h,*J1=x.J;
  const float *A2=y.A,*b2=y.b,*C2=y.C,*h2=y.h,*J2=y.J;
  FE o;
  float Mx[9]; mm(C1,J2,Mx); Mx[0]+=1.0f; Mx[4]+=1.0f; Mx[8]+=1.0f;
  float Mi[9]; inv3(Mx,Mi);
  float T1[9]; mm(A2,Mi,T1);
  mm(T1,A1,o.A);
  float u[3]; mv(C1,h2,u); u[0]+=b1[0]; u[1]+=b1[1]; u[2]+=b1[2];
  mv(T1,u,o.b); o.b[0]+=b2[0]; o.b[1]+=b2[1]; o.b[2]+=b2[2];
  float t2[9]; mm(T1,C1,t2);
  mmnt(t2,A2,o.C);
#pragma unroll
  for (int i=0;i<9;++i) o.C[i]+=C2[i];
  float tmp[9]; mm(Mi,A1,tmp);
  float w[3]; mv(J2,b1,w);
  w[0]=h2[0]-w[0]; w[1]=h2[1]-w[1]; w[2]=h2[2]-w[2];
  mtv(tmp,w,o.h); o.h[0]+=h1[0]; o.h[1]+=h1[1]; o.h[2]+=h1[2];
  float V[9]; mm(J2,A1,V);
  mtn(tmp,V,o.J);
#pragma unroll
  for (int i=0;i<9;++i) o.J[i]+=J1[i];
  symm(o.C); symm(o.J);
  return o;
}
// plain Kalman step (replay)
DEV void fstep(const Model& M, float dt, float obsf, float rf, float Rf_,
               float* m, float* P) {
  float A[9], Q[9]; make_AQ(M, dt, A, Q);
  float mp[3]; mv(A, m, mp);
  float W[9]; mmnt(P, A, W);      // P A^T
  float Pp[9]; mm(A, W, Pp);
#pragma unroll
  for (int i=0;i<9;++i) Pp[i]+=Q[i];
  float S = Pp[0] + Rf_;
  float f = (obsf > 0.5f) ? (1.0f/S) : 0.0f;
  float K0=Pp[0]*f, K1=Pp[3]*f, K2=Pp[6]*f;
  float v = rf - mp[0];
  m[0]=mp[0]+K0*v; m[1]=mp[1]+K1*v; m[2]=mp[2]+K2*v;
  P[0]=Pp[0]-S*K0*K0; P[1]=Pp[1]-S*K0*K1; P[2]=Pp[2]-S*K0*K2;
  P[3]=Pp[3]-S*K1*K0; P[4]=Pp[4]-S*K1*K1; P[5]=Pp[5]-S*K1*K2;
  P[6]=Pp[6]-S*K2*K0; P[7]=Pp[7]-S*K2*K1; P[8]=Pp[8]-S*K2*K2;
  symm(P);
}

// ---------------- smoother affine map: x_k = G x_{k+1} + c ; P_k = G P G^T + U ----------------
struct SE { float G[9]; float c[3]; float U[9]; };

DEV SE se_identity() {
  SE s;
#pragma unroll
  for (int i=0;i<9;++i){ s.G[i]=0.0f; s.U[i]=0.0f; }
  s.G[0]=s.G[4]=s.G[8]=1.0f;
  s.c[0]=s.c[1]=s.c[2]=0.0f;
  return s;
}
DEV void se_store(const SE& s, float* g) {   // contiguous packed-18
#pragma unroll
  for (int i=0;i<9;++i) g[i]=s.G[i];
  g[9]=s.c[0]; g[10]=s.c[1]; g[11]=s.c[2];
  g[12]=s.U[0]; g[13]=s.U[1]; g[14]=s.U[2]; g[15]=s.U[4]; g[16]=s.U[5]; g[17]=s.U[8];
}
DEV SE se_load(const float* g) {
  SE s;
#pragma unroll
  for (int i=0;i<9;++i) s.G[i]=g[i];
  s.c[0]=g[9]; s.c[1]=g[10]; s.c[2]=g[11];
  s.U[0]=g[12]; s.U[1]=g[13]; s.U[2]=g[14];
  s.U[3]=g[13]; s.U[4]=g[15]; s.U[5]=g[16];
  s.U[6]=g[14]; s.U[7]=g[16]; s.U[8]=g[17];
  return s;
}
DEV void se_storeT(const SE& s, float* g, int idx, int n) {  // component-major
#pragma unroll
  for (int i=0;i<9;++i) g[i*n+idx]=s.G[i];
#pragma unroll
  for (int i=0;i<3;++i) g[(9+i)*n+idx]=s.c[i];
  g[12*n+idx]=s.U[0]; g[13*n+idx]=s.U[1]; g[14*n+idx]=s.U[2];
  g[15*n+idx]=s.U[4]; g[16*n+idx]=s.U[5]; g[17*n+idx]=s.U[8];
}
DEV SE se_loadT(const float* g, int idx, int n) {
  SE s;
#pragma unroll
  for (int i=0;i<9;++i) s.G[i]=g[i*n+idx];
#pragma unroll
  for (int i=0;i<3;++i) s.c[i]=g[(9+i)*n+idx];
  float u0=g[12*n+idx], u1=g[13*n+idx], u2=g[14*n+idx],
        u4=g[15*n+idx], u5=g[16*n+idx], u8=g[17*n+idx];
  s.U[0]=u0; s.U[1]=u1; s.U[2]=u2;
  s.U[3]=u1; s.U[4]=u4; s.U[5]=u5;
  s.U[6]=u2; s.U[7]=u5; s.U[8]=u8;
  return s;
}
DEV SE se_shfl_down(const SE& s, int d) {
  SE o;
#pragma unroll
  for (int i=0;i<9;++i) o.G[i]=__shfl_down(s.G[i], d, 64);
#pragma unroll
  for (int i=0;i<3;++i) o.c[i]=__shfl_down(s.c[i], d, 64);
#pragma unroll
  for (int i=0;i<9;++i) o.U[i]=__shfl_down(s.U[i], d, 64);
  return o;
}
// x earlier in time (applied LAST, since smoother runs backward)
DEV SE scompose(const SE& x, const SE& y) {
  SE o;
  mm(x.G, y.G, o.G);
  float t[3]; mv(x.G, y.c, t);
  o.c[0]=t[0]+x.c[0]; o.c[1]=t[1]+x.c[1]; o.c[2]=t[2]+x.c[2];
  float T[9]; mm(x.G, y.U, T);
  mmnt(T, x.G, o.U);
#pragma unroll
  for (int i=0;i<9;++i) o.U[i]+=x.U[i];
  symm(o.U);
  return o;
}
DEV void sapply(const SE& s, float* m, float* P) {
  float t[3]; mv(s.G, m, t);
  float T[9]; mm(s.G, P, T);
  float Pn[9]; mmnt(T, s.G, Pn);
  m[0]=t[0]+s.c[0]; m[1]=t[1]+s.c[1]; m[2]=t[2]+s.c[2];
#pragma unroll
  for (int i=0;i<9;++i) P[i]=Pn[i]+s.U[i];
  symm(P);
}
// build smoother element at global index k (requires k <= T_TOT-2)
DEV SE build_selem(const Model& M, const float4* pk, const float* mf, const float* Pf, int k) {
  float m[3] = { mf[k], mf[T_TOT+k], mf[2*T_TOT+k] };
  float p00=Pf[k], p01=Pf[T_TOT+k], p02=Pf[2*T_TOT+k],
        p11=Pf[3*T_TOT+k], p12=Pf[4*T_TOT+k], p22=Pf[5*T_TOT+k];
  float P[9] = { p00,p01,p02, p01,p11,p12, p02,p12,p22 };
  float dt = pk[k+1].x - pk[k].x;
  SE s;
  float A[9], Q[9]; make_AQ(M, dt, A, Q);
  float W[9]; mmnt(P, A, W);      // P A^T
  float Pp[9]; mm(A, W, Pp);
#pragma unroll
  for (int j=0;j<9;++j) Pp[j]+=Q[j];
  float Pi_[9]; inv3(Pp, Pi_);
  mm(W, Pi_, s.G);                 // G = P A^T Pp^-1
  float mp[3]; mv(A, m, mp);
  float gm[3]; mv(s.G, mp, gm);
  s.c[0]=m[0]-gm[0]; s.c[1]=m[1]-gm[1]; s.c[2]=m[2]-gm[2];
  float GW[9]; mmnt(s.G, W, GW);   // G Pp G^T
#pragma unroll
  for (int j=0;j<9;++j) s.U[j]=P[j]-GW[j];
  symm(s.U);
  return s;
}

// ================= kernels =================
// pk[k] = {time, residual, R, is_obs}  (natural order)
__global__ void k_merge(const float* __restrict__ times, const float* __restrict__ tstar,
                        const float* __restrict__ n1, const float* __restrict__ n2,
                        const float* __restrict__ mcp,
                        float4* pk, int* oix) {
  int g = blockIdx.x*blockDim.x + threadIdx.x;
  if (g >= T_TOT) return;
  float mc = mcp[0];
  if (g < N_TRAIN) {
    int i = g;
    float t = times[i];
    int lo = 0, hi = M_TEST;                 // count tstar strictly < t
    while (lo < hi) { int mid=(lo+hi)>>1; if (tstar[mid] < t) lo=mid+1; else hi=mid; }
    int p = i + lo;
    float s2 = n2[i];
    pk[p] = make_float4(t, n1[i]/s2 - mc, 1.0f/s2, 1.0f);
    oix[p] = -1;
  } else {
    int j = g - N_TRAIN;
    float t = tstar[j];
    int lo = 0, hi = N_TRAIN;                // count times <= t (stable: train first)
    while (lo < hi) { int mid=(lo+hi)>>1; if (times[mid] <= t) lo=mid+1; else hi=mid; }
    int p = j + lo;
    pk[p] = make_float4(t, 0.f, 1.f, 0.f);
    oix[p] = j;
  }
}

// F1: one element per thread, 64-wide shuffle inclusive scan (no LDS, no barriers).
__global__ __launch_bounds__(TPB, 3) void k_f1(
    const float* varp, const float* ellp, const float4* __restrict__ pk,
    float* tIncl, float* blkAgg) {
  int l = threadIdx.x, b = blockIdx.x;
  int t = b*TPB + l;
  Model M = make_model(varp, ellp);
  float4 q = pk[t];
  float dt = (t == 0) ? 0.0f : (q.x - pk[t-1].x);
  FE run = build_felem(M, dt, q.w, q.y, q.z, t == 0);
  for (int d = 1; d < TPB; d <<= 1) {
    FE oth = fe_shfl_up(run, d);
    FE comp = fcompose(oth, run);
    if (l >= d) run = comp;
  }
  fe_storeT(run, tIncl, t, T_TOT);
  if (l == TPB-1) fe_storeT(run, blkAgg, b, NBLK);
}

// F2a: 48 blocks x 64; shuffle-scan 64 block aggregates each -> blkIncl2, group agg.
__global__ __launch_bounds__(TPB, 2) void k_f2a(const float* __restrict__ blkAgg,
                                                float* blkIncl2, float* grpAgg) {
  int l = threadIdx.x, gb = blockIdx.x;
  int b = gb*GRP + l;
  FE run = fe_loadT(blkAgg, b, NBLK);
  for (int d = 1; d < TPB; d <<= 1) {
    FE oth = fe_shfl_up(run, d);
    FE comp = fcompose(oth, run);
    if (l >= d) run = comp;
  }
  fe_storeT(run, blkIncl2, b, NBLK);
  if (l == GRP-1) fe_store(run, grpAgg + gb*FE_S);
}

// F2b: one 64-thread block shuffle-scans the 48 group aggregates -> exclusive prefix.
__global__ __launch_bounds__(TPB, 2) void k_f2b(const float* __restrict__ grpAgg,
                                                float* grpPref) {
  int j = threadIdx.x;
  FE run = (j < NGRP) ? fe_load(grpAgg + j*FE_S) : fe_identity();
  for (int d = 1; d < TPB; d <<= 1) {
    FE oth = fe_shfl_up(run, d);
    FE comp = fcompose(oth, run);
    if (j >= d) run = comp;
  }
  // exclusive prefix: lane j writes lane j-1's inclusive result
  FE X = fe_shfl_up(run, 1);
  if (j < NGRP) {
    if (j == 0) X = fe_identity();
    fe_store(X, grpPref + j*FE_S);
  }
}

// F3: entry = grpPref[g] ∘ blkIncl2[b-1] ∘ tIncl[t-1]; one fstep; store state.
__global__ __launch_bounds__(TPB, 3) void k_f3(
    const float* varp, const float* ellp, const float4* __restrict__ pk,
    const float* __restrict__ tIncl, const float* __restrict__ blkIncl2,
    const float* __restrict__ grpPref,
    float* mf, float* Pf, float* xT) {
  int l = threadIdx.x, b = blockIdx.x;
  int t = b*TPB + l;
  int g = b >> 6, lb = b & (GRP-1);
  Model M = make_model(varp, ellp);
  float m[3], P[9];
  if (t == 0) {
    m[0]=m[1]=m[2]=0.0f; pinf(M, P);
  } else {
    FE gp = fe_load(grpPref + g*FE_S);                         // broadcast
    FE entB = (lb == 0) ? gp : fcompose(gp, fe_loadT(blkIncl2, b-1, NBLK));
    FE ent  = (l == 0) ? entB : fcompose(entB, fe_loadT(tIncl, t-1, T_TOT));
    m[0]=ent.b[0]; m[1]=ent.b[1]; m[2]=ent.b[2];
#pragma unroll
    for (int i=0;i<9;++i) P[i]=ent.C[i];
  }
  float4 q = pk[t];
  float dt = (t == 0) ? 0.0f : (q.x - pk[t-1].x);
  fstep(M, dt, q.w, q.y, q.z, m, P);
  mf[t]=m[0]; mf[T_TOT+t]=m[1]; mf[2*T_TOT+t]=m[2];
  Pf[t]=P[0]; Pf[T_TOT+t]=P[1]; Pf[2*T_TOT+t]=P[2];
  Pf[3*T_TOT+t]=P[4]; Pf[4*T_TOT+t]=P[5]; Pf[5*T_TOT+t]=P[8];
  if (t == T_TOT-1) {
    xT[0]=m[0]; xT[1]=m[1]; xT[2]=m[2];
    xT[3]=P[0]; xT[4]=P[1]; xT[5]=P[2];
    xT[6]=P[4]; xT[7]=P[5]; xT[8]=P[8];
  }
}

// S1: build own smoother element (stored for S3), shuffle backward (suffix) scan.
__global__ __launch_bounds__(TPB, 3) void k_s1(
    const float* varp, const float* ellp, const float4* __restrict__ pk,
    const float* __restrict__ mf, const float* __restrict__ Pf,
    float* eSel, float* tSuf, float* blkAggS) {
  int l = threadIdx.x, b = blockIdx.x;
  int t = b*TPB + l;
  Model M = make_model(varp, ellp);
  SE e = (t <= T_TOT-2) ? build_selem(M, pk, mf, Pf, t) : se_identity();
  se_storeT(e, eSel, t, T_TOT);
  SE Macc = e;
  for (int d = 1; d < TPB; d <<= 1) {
    SE oth = se_shfl_down(Macc, d);
    SE comp = scompose(Macc, oth);
    if (l + d < TPB) Macc = comp;
  }
  se_storeT(Macc, tSuf, t, T_TOT);
  if (l == 0) se_storeT(Macc, blkAggS, b, NBLK);
}

// S2a: 48 blocks x 64; shuffle backward scan of block aggregates -> blkSuf2, group agg.
__global__ __launch_bounds__(TPB, 2) void k_s2a(const float* __restrict__ blkAggS,
                                                float* blkSuf2, float* grpAggS) {
  int l = threadIdx.x, gb = blockIdx.x;
  int b = gb*GRP + l;
  SE run = se_loadT(blkAggS, b, NBLK);
  for (int d = 1; d < TPB; d <<= 1) {
    SE oth = se_shfl_down(run, d);
    SE comp = scompose(run, oth);
    if (l + d < TPB) run = comp;
  }
  se_storeT(run, blkSuf2, b, NBLK);
  if (l == 0) se_store(run, grpAggS + gb*18);
}

// S2b: one 64-thread block backward-scans 48 group aggregates -> gExit[g] =
// smoothed state at first index of group g+1 (last group: xT).
__global__ __launch_bounds__(TPB, 2) void k_s2b(const float* __restrict__ grpAggS,
                                                const float* __restrict__ xT,
                                                float* gExit) {
  int j = threadIdx.x;
  SE run = (j < NGRP) ? se_load(grpAggS + j*18) : se_identity();
  for (int d = 1; d < TPB; d <<= 1) {
    SE oth = se_shfl_down(run, d);
    SE comp = scompose(run, oth);
    if (j + d < TPB) run = comp;
  }
  // suffix of groups j+1.. : shuffle down by 1
  SE Sx = se_shfl_down(run, 1);
  if (j < NGRP) {
    float m[3] = { xT[0], xT[1], xT[2] };
    float P[9] = { xT[3],xT[4],xT[5], xT[4],xT[6],xT[7], xT[5],xT[7],xT[8] };
    if (j < NGRP-1) sapply(Sx, m, P);
    float* o = gExit + j*9;
    o[0]=m[0];o[1]=m[1];o[2]=m[2];o[3]=P[0];o[4]=P[1];o[5]=P[2];o[6]=P[4];o[7]=P[5];o[8]=P[8];
  }
}

// S3: gExit[g] -> (blkSuf2[b+1]) -> (tSuf[t+1]) -> own stored element; write output.
__global__ __launch_bounds__(TPB, 4) void k_s3(
    const float* mcp,
    const float* __restrict__ eSel, const float* __restrict__ tSuf,
    const float* __restrict__ blkSuf2, const float* __restrict__ gExit,
    const int* __restrict__ oix, float* out) {
  int l = threadIdx.x, b = blockIdx.x;
  int t = b*TPB + l;
  int g = b >> 6, lb = b & (GRP-1);
  float mc = mcp[0];
  const float* ge = gExit + g*9;
  float m[3] = { ge[0], ge[1], ge[2] };
  float P[9] = { ge[3],ge[4],ge[5], ge[4],ge[6],ge[7], ge[5],ge[7],ge[8] };
  if (lb < GRP-1) {                  // -> state at first index of block b+1
    SE s = se_loadT(blkSuf2, b+1, NBLK);
    sapply(s, m, P);
  }
  if (l < TPB-1) {                   // -> x_{t+1}
    SE s = se_loadT(tSuf, t+1, T_TOT);
    sapply(s, m, P);
  }
  {                                  // -> x_t (identity element at t == T_TOT-1)
    SE e = se_loadT(eSel, t, T_TOT);
    sapply(e, m, P);
  }
  int j = oix[t];
  if (j >= 0) { out[j] = m[0] + mc; out[M_TEST + j] = fmaxf(P[0], 0.0f); }
}

extern "C" void kernel_launch(void* const* d_in, const int* in_sizes, int n_in,
                              void* d_out, int out_size, void* d_ws, size_t ws_size,
                              hipStream_t stream) {
  const float* times = (const float*)d_in[0];
  const float* tstar = (const float*)d_in[1];
  const float* n1    = (const float*)d_in[2];
  const float* n2    = (const float*)d_in[3];
  const float* varp  = (const float*)d_in[4];
  const float* ellp  = (const float*)d_in[5];
  const float* mcp   = (const float*)d_in[6];
  float* out = (float*)d_out;

  size_t off = 0;
  auto take = [&](size_t bytes) {
    char* p = (char*)d_ws + off;
    off += (bytes + 255) & ~(size_t)255;
    return (void*)p;
  };
  float4* pk     = (float4*)take(sizeof(float4) * T_TOT);
  int*    oix    = (int*)   take(sizeof(int)    * T_TOT);
  float*  mf     = (float*) take(sizeof(float)  * 3 * T_TOT);
  float*  Pf     = (float*) take(sizeof(float)  * 6 * T_TOT);
  float*  tIncl  = (float*) take(sizeof(float)  * FE_S * T_TOT);
  float*  blkAgg = (float*) take(sizeof(float)  * FE_S * NBLK);
  float*  blkIncl2=(float*) take(sizeof(float)  * FE_S * NBLK);
  float*  grpAgg = (float*) take(sizeof(float)  * FE_S * NGRP);
  float*  grpPref= (float*) take(sizeof(float)  * FE_S * NGRP);
  float*  eSel   = (float*) take(sizeof(float)  * 18 * T_TOT);
  float*  tSuf   = (float*) take(sizeof(float)  * 18 * T_TOT);
  float*  blkAggS= (float*) take(sizeof(float)  * 18 * NBLK);
  float*  blkSuf2= (float*) take(sizeof(float)  * 18 * NBLK);
  float*  grpAggS= (float*) take(sizeof(float)  * 18 * NGRP);
  float*  gExit  = (float*) take(sizeof(float)  * 9  * NGRP);
  float*  xT     = (float*) take(sizeof(float)  * 9);
  (void)ws_size; (void)in_sizes; (void)n_in; (void)out_size;

  k_merge<<<(T_TOT+255)/256, 256, 0, stream>>>(times, tstar, n1, n2, mcp, pk, oix);
  k_f1   <<<NBLK, TPB, 0, stream>>>(varp, ellp, pk, tIncl, blkAgg);
  k_f2a  <<<NGRP, TPB, 0, stream>>>(blkAgg, blkIncl2, grpAgg);
  k_f2b  <<<1, TPB, 0, stream>>>(grpAgg, grpPref);
  k_f3   <<<NBLK, TPB, 0, stream>>>(varp, ellp, pk, tIncl, blkIncl2, grpPref, mf, Pf, xT);
  k_s1   <<<NBLK, TPB, 0, stream>>>(varp, ellp, pk, mf, Pf, eSel, tSuf, blkAggS);
  k_s2a  <<<NGRP, TPB, 0, stream>>>(blkAggS, blkSuf2, grpAggS);
  k_s2b  <<<1, TPB, 0, stream>>>(grpAggS, xT, gExit);
  k_s3   <<<NBLK, TPB, 0, stream>>>(mcp, eSel, tSuf, blkSuf2, gExit, oix, out);
}